// Round 14
// baseline (292.752 us; speedup 1.0000x reference)
//
#include <hip/hip_runtime.h>
#include <hip/hip_bf16.h>
#include <cstdint>
#include <math.h>

// ---------------------------------------------------------------------------
// TransformerEncoderBlock — fp32 inputs, fp32 output, bf16 MFMA internals.
//   B=2, N=2048, C=768, H=12, D=64, MLP=3072, M = 4096 tokens
// ROUND 27: proj was occupancy-starved (grid (32,6)=192 blocks on 256 CUs,
// ~25us). Apply the fc2-validated scheme: z=2 K-split (K=384/half, 384
// blocks) + MODE 4 fp32 atomics; the x + proj_b pre-init of x1 is FUSED
// into combine_k (same element offset it already computes; +25MB traffic
// on a 4us kernel, no new launch). x1 overlays qb/kb — dead post-flash;
// combine runs after flash.
// Keep (R13 best-wall config): ones-MFMA l, bias-free exp2 softmax,
// in-reg P-transpose, setprio, 3-buf counted-vmcnt pipelines everywhere,
// m-fastest grids, fc2 z-split atomics + ln2 out-init.
// ---------------------------------------------------------------------------

typedef __bf16 bf16_t;
typedef bf16_t bf16x4 __attribute__((ext_vector_type(4)));
typedef bf16_t bf16x8 __attribute__((ext_vector_type(8)));
typedef float floatx4 __attribute__((ext_vector_type(4)));

#define AS1 __attribute__((address_space(1)))
#define AS3 __attribute__((address_space(3)))

__device__ __forceinline__ void async_load16(const void* g, void* l) {
  const AS1 unsigned int* gp =
      reinterpret_cast<const AS1 unsigned int*>(reinterpret_cast<uintptr_t>(g));
  AS3 unsigned int* lp = reinterpret_cast<AS3 unsigned int*>(
      static_cast<unsigned int>(reinterpret_cast<uintptr_t>(l)));
  __builtin_amdgcn_global_load_lds(gp, lp, 16, 0, 0);
}

__device__ __forceinline__ bf16x8 lds_read8(const bf16_t* p) {
  return *reinterpret_cast<const bf16x8*>(p);
}

// ---------------------------------------------------------------------------
__global__ __launch_bounds__(256) void cvt_k(const float* __restrict__ in,
                                             bf16_t* __restrict__ out, int n4) {
  const int i = blockIdx.x * 256 + threadIdx.x;
  if (i < n4) {
    const float4 v = reinterpret_cast<const float4*>(in)[i];
    bf16x4 o;
    o[0] = (bf16_t)v.x; o[1] = (bf16_t)v.y; o[2] = (bf16_t)v.z; o[3] = (bf16_t)v.w;
    reinterpret_cast<bf16x4*>(out)[i] = o;
  }
}

// all four weights in one launch (big-ws path). i4 ranges:
// qkv [0,442368) proj [442368,589824) fc1 [589824,1179648) fc2 [1179648,1769472)
__global__ __launch_bounds__(256) void cvt_all_k(
    const float* __restrict__ s0, const float* __restrict__ s1,
    const float* __restrict__ s2, const float* __restrict__ s3,
    bf16_t* __restrict__ d0, bf16_t* __restrict__ d1, bf16_t* __restrict__ d2,
    bf16_t* __restrict__ d3) {
  int i = blockIdx.x * 256 + threadIdx.x;
  const float* src;
  bf16_t* dst;
  if (i < 442368) { src = s0; dst = d0; }
  else if (i < 589824) { src = s1; dst = d1; i -= 442368; }
  else if (i < 1179648) { src = s2; dst = d2; i -= 589824; }
  else if (i < 1769472) { src = s3; dst = d3; i -= 1179648; }
  else return;
  const float4 v = reinterpret_cast<const float4*>(src)[i];
  bf16x4 o;
  o[0] = (bf16_t)v.x; o[1] = (bf16_t)v.y; o[2] = (bf16_t)v.z; o[3] = (bf16_t)v.w;
  reinterpret_cast<bf16x4*>(dst)[i] = o;
}

// ---------------------------------------------------------------------------
// LayerNorm. INIT=1 additionally writes oinit[row][c] = x[row][c] + b2[c]
// (pre-initializes the fc2 output with residual + bias so fc2 can atomic-add).
// ---------------------------------------------------------------------------
template <int INIT>
__global__ __launch_bounds__(256) void ln_k(const float* __restrict__ x,
                                            const float* __restrict__ g,
                                            const float* __restrict__ b,
                                            bf16_t* __restrict__ out,
                                            const float* __restrict__ b2,
                                            float* __restrict__ oinit) {
  const int row = blockIdx.x;
  const int tid = threadIdx.x;
  const float* xr = x + (long)row * 768;
  float v[3];
#pragma unroll
  for (int e = 0; e < 3; e++) v[e] = xr[tid + e * 256];
  float s = v[0] + v[1] + v[2];
  float ss = v[0] * v[0] + v[1] * v[1] + v[2] * v[2];
#pragma unroll
  for (int off = 32; off >= 1; off >>= 1) {
    s += __shfl_down(s, off, 64);
    ss += __shfl_down(ss, off, 64);
  }
  __shared__ float red[8];
  __shared__ float stat[2];
  const int wv = tid >> 6;
  if ((tid & 63) == 0) { red[wv] = s; red[4 + wv] = ss; }
  __syncthreads();
  if (tid == 0) {
    float S = red[0] + red[1] + red[2] + red[3];
    float SS = red[4] + red[5] + red[6] + red[7];
    float mu = S * (1.0f / 768.0f);
    float var = SS * (1.0f / 768.0f) - mu * mu;
    stat[0] = mu;
    stat[1] = rsqrtf(var + 1e-5f);
  }
  __syncthreads();
  const float mu = stat[0], rs = stat[1];
#pragma unroll
  for (int e = 0; e < 3; e++) {
    int c = tid + e * 256;
    out[(long)row * 768 + c] = (bf16_t)((v[e] - mu) * rs * g[c] + b[c]);
    if constexpr (INIT == 1) oinit[(long)row * 768 + c] = v[e] + b2[c];
  }
}

// ---------------------------------------------------------------------------
// GEMM 128x128 tile, BK=32, 3-buf LDS, 2-deep prefetch, counted vmcnt.
// Grid: blockIdx.x = m-tile (fastest), blockIdx.y = n-tile,
// blockIdx.z = K-split (kOff = z*keff).
// MODE 0: QKV scatter (q scaled 0.125*log2e for bias-free flash exp2;
//         q,k:[bh,t,d]; v:[bh,d,t])
// MODE 2: + bias + exact GELU -> bf16 out (ld Nld)
// MODE 4: unsafeAtomicAdd(out_f, acc) (fp32; out pre-initialized with
//         residual+bias — used by proj and fc2)
// LDS 48KB -> 2 blocks/CU at (256,2).
// ---------------------------------------------------------------------------
template <int MODE>
__global__ __launch_bounds__(256, 2) void gemm_k(
    const bf16_t* __restrict__ A, const bf16_t* __restrict__ Bt, int lda,
    int ldb, int keff, int Nld, const float* __restrict__ bias,
    bf16_t* __restrict__ out_bf, bf16_t* __restrict__ q_out,
    bf16_t* __restrict__ k_out, bf16_t* __restrict__ vt_out,
    const float* __restrict__ resid_f, float* __restrict__ out_f) {
  constexpr int BK = 32;
  __shared__ __align__(16) bf16_t As[3][128 * BK];
  __shared__ __align__(16) bf16_t Bs[3][128 * BK];

  const int tid = threadIdx.x;
  const int w = tid >> 6;
  const int lane = tid & 63;
  const int quad = lane >> 4;
  const int lid = lane & 15;
  const int wr = (w >> 1) * 64;
  const int wc = (w & 1) * 64;
  const int mBase = blockIdx.x * 128;  // m fastest
  const int nBase = blockIdx.y * 128;
  const int kOff = blockIdx.z * keff;

  const int ldsRowSub = lane >> 2;
  const int kblk = (lane & 3) ^ (ldsRowSub & 3) ^ ((ldsRowSub >> 2) & 3);
  const int rq0 = (quad ^ (lid & 3) ^ ((lid >> 2) & 3)) * 8;
  const int c0 = w * 2, c1 = w * 2 + 1;
  const int rowA0 = c0 * 16 + ldsRowSub, rowA1 = c1 * 16 + ldsRowSub;

  const bf16_t* Ag = A + (long)mBase * lda + kOff;
  const bf16_t* Bg = Bt + (long)nBase * ldb + kOff;

  floatx4 acc[4][4];
#pragma unroll
  for (int i = 0; i < 4; i++)
#pragma unroll
    for (int j = 0; j < 4; j++) acc[i][j] = (floatx4){0.f, 0.f, 0.f, 0.f};

  auto stage = [&](int b, int k0) {
    async_load16(Ag + (long)rowA0 * lda + k0 + kblk * 8, &As[b][c0 * 512]);
    async_load16(Ag + (long)rowA1 * lda + k0 + kblk * 8, &As[b][c1 * 512]);
    async_load16(Bg + (long)rowA0 * ldb + k0 + kblk * 8, &Bs[b][c0 * 512]);
    async_load16(Bg + (long)rowA1 * ldb + k0 + kblk * 8, &Bs[b][c1 * 512]);
  };

  const int iters = keff / BK;
  stage(0, 0);
  stage(1, BK);

  int cur = 0;
  for (int it = 0; it < iters; it++) {
    // tile `it` landed (own 4 loads done; next tile's 4 may stay in flight);
    // lgkmcnt(0): our ds_reads of the buffer about to be re-staged are done.
    if (it + 1 < iters)
      asm volatile("s_waitcnt vmcnt(4) lgkmcnt(0)" ::: "memory");
    else
      asm volatile("s_waitcnt vmcnt(0) lgkmcnt(0)" ::: "memory");
    __builtin_amdgcn_s_barrier();
    if (it + 2 < iters) {
      int nb = cur + 2; if (nb >= 3) nb -= 3;
      stage(nb, (it + 2) * BK);
    }

    bf16x8 af[4], bfv[4];
#pragma unroll
    for (int i = 0; i < 4; i++)
      af[i] = lds_read8(&As[cur][(wr + i * 16 + lid) * BK + rq0]);
#pragma unroll
    for (int j = 0; j < 4; j++)
      bfv[j] = lds_read8(&Bs[cur][(wc + j * 16 + lid) * BK + rq0]);
#pragma unroll
    for (int i = 0; i < 4; i++)
#pragma unroll
      for (int j = 0; j < 4; j++)
        acc[i][j] = __builtin_amdgcn_mfma_f32_16x16x32_bf16(af[i], bfv[j],
                                                            acc[i][j], 0, 0, 0);
    cur = (cur == 2) ? 0 : cur + 1;
  }

#pragma unroll
  for (int i = 0; i < 4; i++) {
    const int mRow = mBase + wr + i * 16 + quad * 4;
#pragma unroll
    for (int j = 0; j < 4; j++) {
      const int n = nBase + wc + j * 16 + lid;
      if constexpr (MODE == 0) {
        const int which = n / 768;
        const int rem = n - which * 768;
        const int head = rem >> 6;
        const int d = rem & 63;
        const int b = mRow >> 11;
        const int t = mRow & 2047;
        const int bh = b * 12 + head;
        if (which == 2) {
          bf16x4 pk;
#pragma unroll
          for (int r = 0; r < 4; r++) pk[r] = (bf16_t)acc[i][j][r];
          const long off = ((long)bh * 64 + d) * 2048 + t;
          *reinterpret_cast<bf16x4*>(&vt_out[off]) = pk;
        } else if (which == 0) {
          // q scale folds softmax's log2e: flash computes p = exp2(s) direct
#pragma unroll
          for (int r = 0; r < 4; r++)
            q_out[((long)bh * 2048 + t + r) * 64 + d] =
                (bf16_t)(acc[i][j][r] * (0.125f * 1.44269504f));
        } else {
#pragma unroll
          for (int r = 0; r < 4; r++)
            k_out[((long)bh * 2048 + t + r) * 64 + d] = (bf16_t)acc[i][j][r];
        }
      } else if constexpr (MODE == 2) {  // GELU
        const float bv = bias[n];
#pragma unroll
        for (int r = 0; r < 4; r++) {
          float v = acc[i][j][r] + bv;
          float ge = 0.5f * v * (1.0f + erff(v * 0.70710678118654752f));
          out_bf[(long)(mRow + r) * Nld + n] = (bf16_t)ge;
        }
      } else {  // MODE 4: HW fp32 atomic accumulate (out pre-initialized)
#pragma unroll
        for (int r = 0; r < 4; r++) {
          const long off = (long)(mRow + r) * Nld + n;
          unsafeAtomicAdd(&out_f[off], acc[i][j][r]);
        }
      }
    }
  }
}

// ---------------------------------------------------------------------------
// Flash v10: 512 threads (8 waves x 16 qrows), QT=128, SK=64.
// Grid (16, 24, 2): z = K-half (1024 tokens = 16 chunks each).
// 3-buffer K/V staging, 2-deep prefetch, counted vmcnt.
// Bias-free softmax (q pre-scaled 0.125*log2e -> p = exp2(s)).
// In-register P-transpose (v_cvt_pk_bf16_f32 + permlane32/16_swap).
// l via ones-MFMA (D-layout, lanes lid==0 write 4 rows each).
// setprio around MFMA clusters.
// Outputs UNNORMALIZED U (bf16, [half][bh][t][d]) and l (fp32).
// ---------------------------------------------------------------------------
__global__ __launch_bounds__(512, 1) void flash_k(const bf16_t* __restrict__ q,
                                                  const bf16_t* __restrict__ kk,
                                                  const bf16_t* __restrict__ vt,
                                                  bf16_t* __restrict__ U,
                                                  float* __restrict__ lbuf) {
  constexpr int SK = 64, D = 64;
  __shared__ __align__(16) bf16_t Ks[3][SK * D];
  __shared__ __align__(16) bf16_t Vs[3][D * SK];

  const int tid = threadIdx.x;
  const int w = tid >> 6;         // 0..7
  const int lane = tid & 63;
  const int quad = lane >> 4;
  const int lid = lane & 15;
  const int bh = blockIdx.y;
  const int half = blockIdx.z;
  const int qBase = blockIdx.x * 128;

  const bf16_t* qg = q + ((long)bh * 2048 + qBase) * D;
  const bf16_t* kg = kk + ((long)bh * 2048 + half * 1024) * D;
  const bf16_t* vg = vt + (long)bh * D * 2048 + half * 1024;

  // Q fragment in registers: B-operand, qrow = w*16+lid
  bf16x8 aq[2];
#pragma unroll
  for (int k2 = 0; k2 < 2; k2++)
    aq[k2] = *reinterpret_cast<const bf16x8*>(qg + (w * 16 + lid) * D +
                                              k2 * 32 + quad * 8);

  // all-ones B-fragment for the l-MFMA
  const bf16_t one = (bf16_t)1.0f;
  const bf16x8 vones = {one, one, one, one, one, one, one, one};

  const int srow = lane >> 3;           // 0..7
  const int sdb = (lane & 7) ^ srow;    // swizzled 16B block
  const int rsw = lid & 7;

  // wave w stages rows w*8..w*8+7 of K and V for chunk kc
  auto stagef = [&](int b, int kc) {
    async_load16(kg + (long)(kc + w * 8 + srow) * D + sdb * 8, &Ks[b][w * 512]);
    async_load16(vg + (long)(w * 8 + srow) * 2048 + kc + sdb * 8, &Vs[b][w * 512]);
  };

  stagef(0, 0);
  stagef(1, 64);

  floatx4 lacc = (floatx4){0.f, 0.f, 0.f, 0.f};
  floatx4 oacc[4];
#pragma unroll
  for (int jo = 0; jo < 4; jo++) oacc[jo] = (floatx4){0.f, 0.f, 0.f, 0.f};

  int cur = 0;
  for (int kci = 0; kci < 16; kci++) {
    // tile kci landed (own 2 loads done; tile kci+1's 2 may stay in flight);
    // lgkmcnt(0): my ds_reads of the buffer about to be re-staged are done.
    if (kci + 1 < 16)
      asm volatile("s_waitcnt vmcnt(2) lgkmcnt(0)" ::: "memory");
    else
      asm volatile("s_waitcnt vmcnt(0) lgkmcnt(0)" ::: "memory");
    __builtin_amdgcn_s_barrier();
    if (kci + 2 < 16) {
      int nb = cur + 2; if (nb >= 3) nb -= 3;
      stagef(nb, (kci + 2) * 64);
    }

    // S^T = K Q^T  — sacc[jm] holds S[kt=jm*16+quad*4+r][q=lid]
    floatx4 sacc[4];
#pragma unroll
    for (int jm = 0; jm < 4; jm++) sacc[jm] = (floatx4){0.f, 0.f, 0.f, 0.f};
    __builtin_amdgcn_s_setprio(1);
#pragma unroll
    for (int k2 = 0; k2 < 2; k2++) {
#pragma unroll
      for (int jm = 0; jm < 4; jm++) {
        const bf16x8 ak = lds_read8(
            &Ks[cur][(jm * 16 + lid) * D + (((k2 * 4 + quad) ^ rsw) * 8)]);
        sacc[jm] =
            __builtin_amdgcn_mfma_f32_16x16x32_bf16(ak, aq[k2], sacc[jm], 0, 0, 0);
      }
    }
    __builtin_amdgcn_s_setprio(0);

    // p = exp2(s) (bias-free; log2e folded into q scale);
    // pack bf16 pairs; permlane-rotate to PV A-fragment layout.
    bf16x8 ap[2];
#pragma unroll
    for (int k2 = 0; k2 < 2; k2++) {
      uint32_t pk[2][2];
#pragma unroll
      for (int j = 0; j < 2; j++) {
        const int jm = k2 * 2 + j;
        const float p0 = exp2f(sacc[jm][0]);
        const float p1 = exp2f(sacc[jm][1]);
        const float p2 = exp2f(sacc[jm][2]);
        const float p3 = exp2f(sacc[jm][3]);
        asm("v_cvt_pk_bf16_f32 %0, %1, %2" : "=v"(pk[j][0]) : "v"(p0), "v"(p1));
        asm("v_cvt_pk_bf16_f32 %0, %1, %2" : "=v"(pk[j][1]) : "v"(p2), "v"(p3));
      }
      asm("v_permlane32_swap_b32 %0, %1" : "+v"(pk[0][0]), "+v"(pk[1][0]));
      asm("v_permlane16_swap_b32 %0, %1" : "+v"(pk[0][0]), "+v"(pk[1][0]));
      asm("v_permlane32_swap_b32 %0, %1" : "+v"(pk[0][1]), "+v"(pk[1][1]));
      asm("v_permlane16_swap_b32 %0, %1" : "+v"(pk[0][1]), "+v"(pk[1][1]));
      union { uint32_t u[4]; bf16x8 v; } au;
      au.u[0] = pk[0][0];  // kt +0,+1
      au.u[1] = pk[0][1];  // kt +2,+3
      au.u[2] = pk[1][0];  // kt +4,+5
      au.u[3] = pk[1][1];  // kt +6,+7
      ap[k2] = au.v;
    }

    // O += P V; l += P 1 (ones-MFMA: D[q][.] = sum_kt P[q][kt])
    __builtin_amdgcn_s_setprio(1);
#pragma unroll
    for (int k2 = 0; k2 < 2; k2++) {
#pragma unroll
      for (int jo = 0; jo < 4; jo++) {
        const bf16x8 bv = lds_read8(
            &Vs[cur][(jo * 16 + lid) * SK + (((k2 * 4 + quad) ^ rsw) * 8)]);
        oacc[jo] =
            __builtin_amdgcn_mfma_f32_16x16x32_bf16(ap[k2], bv, oacc[jo], 0, 0, 0);
      }
      lacc = __builtin_amdgcn_mfma_f32_16x16x32_bf16(ap[k2], vones, lacc, 0, 0, 0);
    }
    __builtin_amdgcn_s_setprio(0);
    cur = (cur == 2) ? 0 : cur + 1;
  }

  // store l: lacc[r] = l for qrow quad*4+r (replicated across lid);
  // lanes with lid==0 (one per quad) write 4 rows each.
  const long lrow = ((long)half * 24 + bh) * 2048 + qBase + w * 16;
  if (lid == 0) {
#pragma unroll
    for (int r = 0; r < 4; r++) lbuf[lrow + quad * 4 + r] = lacc[r];
  }

  // store unnormalized U[half][bh][t][d]
  bf16_t* Ub = U + (((long)half * 24 + bh) * 2048 + qBase) * D;
#pragma unroll
  for (int jo = 0; jo < 4; jo++) {
#pragma unroll
    for (int r = 0; r < 4; r++) {
      const int t = w * 16 + quad * 4 + r;
      Ub[(long)t * D + jo * 16 + lid] = (bf16_t)oacc[jo][r];
    }
  }
}

// ---------------------------------------------------------------------------
// Combine: o[b][t][head*64+d] = (U0+U1)/(l0+l1)
// FUSED: x1[same offset] = x[same offset] + proj_b[c] — pre-initializes
// proj's output so proj can run z-split with fp32 atomics (MODE 4).
// ---------------------------------------------------------------------------
__global__ __launch_bounds__(256) void combine_k(const bf16_t* __restrict__ U,
                                                 const float* __restrict__ lbuf,
                                                 bf16_t* __restrict__ o,
                                                 const float* __restrict__ x,
                                                 const float* __restrict__ pb,
                                                 float* __restrict__ x1) {
  const int idx = blockIdx.x * 256 + threadIdx.x;  // < 3145728
  const int bh = idx >> 17;
  const int rem = idx & 131071;
  const int t = rem >> 6;
  const int d = rem & 63;
  const float l0 = lbuf[bh * 2048 + t];
  const float l1 = lbuf[(24 + bh) * 2048 + t];
  const float u = (float)U[idx] + (float)U[3145728 + idx];
  const int b = bh / 12;
  const int head = bh - b * 12;
  const int c = head * 64 + d;
  const long oo = ((long)b * 2048 + t) * 768 + c;
  o[oo] = (bf16_t)(u / (l0 + l1));
  x1[oo] = x[oo] + pb[c];
}

// ---------------------------------------------------------------------------
extern "C" void kernel_launch(void* const* d_in, const int* in_sizes, int n_in,
                              void* d_out, int out_size, void* d_ws,
                              size_t ws_size, hipStream_t stream) {
  (void)in_sizes; (void)n_in; (void)out_size;
  const float* x = (const float*)d_in[0];
  const float* ln1_g = (const float*)d_in[1];
  const float* ln1_b = (const float*)d_in[2];
  const float* qkv_w = (const float*)d_in[3];
  const float* proj_w = (const float*)d_in[4];
  const float* proj_b = (const float*)d_in[5];
  const float* ln2_g = (const float*)d_in[6];
  const float* ln2_b = (const float*)d_in[7];
  const float* fc1_w = (const float*)d_in[8];
  const float* fc1_b = (const float*)d_in[9];
  const float* fc2_w = (const float*)d_in[10];
  const float* fc2_b = (const float*)d_in[11];
  float* out = (float*)d_out;
  char* ws = (char*)d_ws;

  const bool big = ws_size >= (size_t)64487424;

  if (big) {
    // big layout:
    // wqkv[0,3538944) wproj[3538944,4718592) wfc1[4718592,9437184)
    // wfc2[9437184,14155776) h1/ob[14155776,20447232) qb[20447232,26738688)
    // kb[26738688,33030144) vtb[33030144,39321600)
    // U[39321600,51904512) l[51904512,52297728)
    // x1 over qb+kb [20447232,33030144); h2 over vtb; hg [39321600,64487424)
    bf16_t* wqkv = (bf16_t*)(ws + 0);
    bf16_t* wproj = (bf16_t*)(ws + 3538944);
    bf16_t* wfc1 = (bf16_t*)(ws + 4718592);
    bf16_t* wfc2 = (bf16_t*)(ws + 9437184);
    bf16_t* h1 = (bf16_t*)(ws + 14155776);
    bf16_t* ob = h1;
    bf16_t* qb = (bf16_t*)(ws + 20447232);
    bf16_t* kb = (bf16_t*)(ws + 26738688);
    bf16_t* vtb = (bf16_t*)(ws + 33030144);
    bf16_t* Ubuf = (bf16_t*)(ws + 39321600);
    float* lbuf = (float*)(ws + 51904512);
    float* x1 = (float*)(ws + 20447232);
    bf16_t* h2 = (bf16_t*)(ws + 33030144);
    bf16_t* hg = (bf16_t*)(ws + 39321600);

    cvt_all_k<<<6912, 256, 0, stream>>>(qkv_w, proj_w, fc1_w, fc2_w, wqkv,
                                        wproj, wfc1, wfc2);
    ln_k<0><<<4096, 256, 0, stream>>>(x, ln1_g, ln1_b, h1, nullptr, nullptr);
    gemm_k<0><<<dim3(32, 18), 256, 0, stream>>>(h1, wqkv, 768, 768, 768, 2304,
                                                nullptr, nullptr, qb, kb, vtb,
                                                nullptr, nullptr);
    flash_k<<<dim3(16, 24, 2), 512, 0, stream>>>(qb, kb, vtb, Ubuf, lbuf);
    combine_k<<<12288, 256, 0, stream>>>(Ubuf, lbuf, ob, x, proj_b, x1);
    gemm_k<4><<<dim3(32, 6, 2), 256, 0, stream>>>(ob, wproj, 768, 768, 384, 768,
                                                  nullptr, nullptr, nullptr,
                                                  nullptr, nullptr, nullptr,
                                                  x1);
    ln_k<1><<<4096, 256, 0, stream>>>(x1, ln2_g, ln2_b, h2, fc2_b, out);
    gemm_k<2><<<dim3(32, 24), 256, 0, stream>>>(h2, wfc1, 768, 768, 768, 3072,
                                                fc1_b, hg, nullptr, nullptr,
                                                nullptr, nullptr, nullptr);
    gemm_k<4><<<dim3(32, 6, 2), 256, 0, stream>>>(hg, wfc2, 3072, 3072, 1536,
                                                  768, nullptr, nullptr,
                                                  nullptr, nullptr, nullptr,
                                                  nullptr, out);
  } else {
    // small layout (r12) + U/l in the free tail
    bf16_t* wqkv = (bf16_t*)(ws + 0);
    bf16_t* wproj = (bf16_t*)(ws + 3538944);
    bf16_t* h1 = (bf16_t*)(ws + 4718592);
    bf16_t* ob = h1;
    bf16_t* qb = (bf16_t*)(ws + 11010048);
    bf16_t* kb = (bf16_t*)(ws + 17301504);
    bf16_t* vtb = (bf16_t*)(ws + 23592960);
    float* x1 = (float*)(ws + 11010048);
    bf16_t* h2 = (bf16_t*)(ws + 23592960);
    bf16_t* wfc1 = (bf16_t*)(ws + 0);
    bf16_t* wfc2 = (bf16_t*)(ws + 4718592);
    bf16_t* hg = (bf16_t*)(ws + 29884416);
    bf16_t* Ubuf = (bf16_t*)(ws + 29884416);  // dead before hg is written
    float* lbuf = (float*)(ws + 42467328);

    cvt_k<<<1728, 256, 0, stream>>>(qkv_w, wqkv, 442368);
    cvt_k<<<576, 256, 0, stream>>>(proj_w, wproj, 147456);
    ln_k<0><<<4096, 256, 0, stream>>>(x, ln1_g, ln1_b, h1, nullptr, nullptr);
    gemm_k<0><<<dim3(32, 18), 256, 0, stream>>>(h1, wqkv, 768, 768, 768, 2304,
                                                nullptr, nullptr, qb, kb, vtb,
                                                nullptr, nullptr);
    flash_k<<<dim3(16, 24, 2), 512, 0, stream>>>(qb, kb, vtb, Ubuf, lbuf);
    combine_k<<<12288, 256, 0, stream>>>(Ubuf, lbuf, ob, x, proj_b, x1);
    gemm_k<4><<<dim3(32, 6, 2), 256, 0, stream>>>(ob, wproj, 768, 768, 384, 768,
                                                  nullptr, nullptr, nullptr,
                                                  nullptr, nullptr, nullptr,
                                                  x1);
    cvt_k<<<2304, 256, 0, stream>>>(fc1_w, wfc1, 589824);
    cvt_k<<<2304, 256, 0, stream>>>(fc2_w, wfc2, 589824);
    ln_k<1><<<4096, 256, 0, stream>>>(x1, ln2_g, ln2_b, h2, fc2_b, out);
    for (int h = 0; h < 2; h++) {
      gemm_k<2><<<dim3(32, 12), 256, 0, stream>>>(
          h2, wfc1 + (long)h * 1536 * 768, 768, 768, 768, 1536,
          fc1_b + h * 1536, hg, nullptr, nullptr, nullptr, nullptr, nullptr);
      gemm_k<4><<<dim3(32, 6), 256, 0, stream>>>(hg, wfc2 + h * 1536, 1536,
                                                 3072, 1536, 768, nullptr,
                                                 nullptr, nullptr, nullptr,
                                                 nullptr, nullptr, out);
    }
  }
}

// Round 15
// 270.222 us; speedup vs baseline: 1.0834x; 1.0834x over previous
//
#include <hip/hip_runtime.h>
#include <hip/hip_bf16.h>
#include <cstdint>
#include <math.h>

// ---------------------------------------------------------------------------
// TransformerEncoderBlock — fp32 inputs, fp32 output, bf16 MFMA internals.
//   B=2, N=2048, C=768, H=12, D=64, MLP=3072, M = 4096 tokens
// ROUND 28 == ROUND 26 config (best measured wall 270.4us): R14's proj
// z-split regressed (+22us: combine +25MB fp32 traffic, proj 2x atomic
// RMW + poor 12-iter pipeline amortization — z-split needs deep K).
// Config: ones-MFMA l, bias-free exp2 softmax (log2e folded into q scale),
// in-reg P-transpose (cvt_pk + permlane32/16_swap), setprio on MFMA,
// 3-buf counted-vmcnt pipelines in all gemms + flash, m-fastest grids,
// proj = MODE 3 (fused resid+bias epilogue), fc2 = z-split MODE 4 atomics
// with ln2 out-init.
// ---------------------------------------------------------------------------

typedef __bf16 bf16_t;
typedef bf16_t bf16x4 __attribute__((ext_vector_type(4)));
typedef bf16_t bf16x8 __attribute__((ext_vector_type(8)));
typedef float floatx4 __attribute__((ext_vector_type(4)));

#define AS1 __attribute__((address_space(1)))
#define AS3 __attribute__((address_space(3)))

__device__ __forceinline__ void async_load16(const void* g, void* l) {
  const AS1 unsigned int* gp =
      reinterpret_cast<const AS1 unsigned int*>(reinterpret_cast<uintptr_t>(g));
  AS3 unsigned int* lp = reinterpret_cast<AS3 unsigned int*>(
      static_cast<unsigned int>(reinterpret_cast<uintptr_t>(l)));
  __builtin_amdgcn_global_load_lds(gp, lp, 16, 0, 0);
}

__device__ __forceinline__ bf16x8 lds_read8(const bf16_t* p) {
  return *reinterpret_cast<const bf16x8*>(p);
}

// ---------------------------------------------------------------------------
__global__ __launch_bounds__(256) void cvt_k(const float* __restrict__ in,
                                             bf16_t* __restrict__ out, int n4) {
  const int i = blockIdx.x * 256 + threadIdx.x;
  if (i < n4) {
    const float4 v = reinterpret_cast<const float4*>(in)[i];
    bf16x4 o;
    o[0] = (bf16_t)v.x; o[1] = (bf16_t)v.y; o[2] = (bf16_t)v.z; o[3] = (bf16_t)v.w;
    reinterpret_cast<bf16x4*>(out)[i] = o;
  }
}

// all four weights in one launch (big-ws path). i4 ranges:
// qkv [0,442368) proj [442368,589824) fc1 [589824,1179648) fc2 [1179648,1769472)
__global__ __launch_bounds__(256) void cvt_all_k(
    const float* __restrict__ s0, const float* __restrict__ s1,
    const float* __restrict__ s2, const float* __restrict__ s3,
    bf16_t* __restrict__ d0, bf16_t* __restrict__ d1, bf16_t* __restrict__ d2,
    bf16_t* __restrict__ d3) {
  int i = blockIdx.x * 256 + threadIdx.x;
  const float* src;
  bf16_t* dst;
  if (i < 442368) { src = s0; dst = d0; }
  else if (i < 589824) { src = s1; dst = d1; i -= 442368; }
  else if (i < 1179648) { src = s2; dst = d2; i -= 589824; }
  else if (i < 1769472) { src = s3; dst = d3; i -= 1179648; }
  else return;
  const float4 v = reinterpret_cast<const float4*>(src)[i];
  bf16x4 o;
  o[0] = (bf16_t)v.x; o[1] = (bf16_t)v.y; o[2] = (bf16_t)v.z; o[3] = (bf16_t)v.w;
  reinterpret_cast<bf16x4*>(dst)[i] = o;
}

// ---------------------------------------------------------------------------
// LayerNorm. INIT=1 additionally writes oinit[row][c] = x[row][c] + b2[c]
// (pre-initializes the fc2 output with residual + bias so fc2 can atomic-add).
// ---------------------------------------------------------------------------
template <int INIT>
__global__ __launch_bounds__(256) void ln_k(const float* __restrict__ x,
                                            const float* __restrict__ g,
                                            const float* __restrict__ b,
                                            bf16_t* __restrict__ out,
                                            const float* __restrict__ b2,
                                            float* __restrict__ oinit) {
  const int row = blockIdx.x;
  const int tid = threadIdx.x;
  const float* xr = x + (long)row * 768;
  float v[3];
#pragma unroll
  for (int e = 0; e < 3; e++) v[e] = xr[tid + e * 256];
  float s = v[0] + v[1] + v[2];
  float ss = v[0] * v[0] + v[1] * v[1] + v[2] * v[2];
#pragma unroll
  for (int off = 32; off >= 1; off >>= 1) {
    s += __shfl_down(s, off, 64);
    ss += __shfl_down(ss, off, 64);
  }
  __shared__ float red[8];
  __shared__ float stat[2];
  const int wv = tid >> 6;
  if ((tid & 63) == 0) { red[wv] = s; red[4 + wv] = ss; }
  __syncthreads();
  if (tid == 0) {
    float S = red[0] + red[1] + red[2] + red[3];
    float SS = red[4] + red[5] + red[6] + red[7];
    float mu = S * (1.0f / 768.0f);
    float var = SS * (1.0f / 768.0f) - mu * mu;
    stat[0] = mu;
    stat[1] = rsqrtf(var + 1e-5f);
  }
  __syncthreads();
  const float mu = stat[0], rs = stat[1];
#pragma unroll
  for (int e = 0; e < 3; e++) {
    int c = tid + e * 256;
    out[(long)row * 768 + c] = (bf16_t)((v[e] - mu) * rs * g[c] + b[c]);
    if constexpr (INIT == 1) oinit[(long)row * 768 + c] = v[e] + b2[c];
  }
}

// ---------------------------------------------------------------------------
// GEMM 128x128 tile, BK=32, 3-buf LDS, 2-deep prefetch, counted vmcnt.
// Grid: blockIdx.x = m-tile (fastest), blockIdx.y = n-tile,
// blockIdx.z = K-split (kOff = z*keff).
// MODE 0: QKV scatter (q scaled 0.125*log2e for bias-free flash exp2;
//         q,k:[bh,t,d]; v:[bh,d,t])
// MODE 2: + bias + exact GELU -> bf16 out (ld Nld)
// MODE 3: out_f = resid_f + acc + bias (fp32, proj)
// MODE 4: unsafeAtomicAdd(out_f, acc) (fp32, fc2; out pre-initialized)
// LDS 48KB -> 2 blocks/CU at (256,2).
// ---------------------------------------------------------------------------
template <int MODE>
__global__ __launch_bounds__(256, 2) void gemm_k(
    const bf16_t* __restrict__ A, const bf16_t* __restrict__ Bt, int lda,
    int ldb, int keff, int Nld, const float* __restrict__ bias,
    bf16_t* __restrict__ out_bf, bf16_t* __restrict__ q_out,
    bf16_t* __restrict__ k_out, bf16_t* __restrict__ vt_out,
    const float* __restrict__ resid_f, float* __restrict__ out_f) {
  constexpr int BK = 32;
  __shared__ __align__(16) bf16_t As[3][128 * BK];
  __shared__ __align__(16) bf16_t Bs[3][128 * BK];

  const int tid = threadIdx.x;
  const int w = tid >> 6;
  const int lane = tid & 63;
  const int quad = lane >> 4;
  const int lid = lane & 15;
  const int wr = (w >> 1) * 64;
  const int wc = (w & 1) * 64;
  const int mBase = blockIdx.x * 128;  // m fastest
  const int nBase = blockIdx.y * 128;
  const int kOff = blockIdx.z * keff;

  const int ldsRowSub = lane >> 2;
  const int kblk = (lane & 3) ^ (ldsRowSub & 3) ^ ((ldsRowSub >> 2) & 3);
  const int rq0 = (quad ^ (lid & 3) ^ ((lid >> 2) & 3)) * 8;
  const int c0 = w * 2, c1 = w * 2 + 1;
  const int rowA0 = c0 * 16 + ldsRowSub, rowA1 = c1 * 16 + ldsRowSub;

  const bf16_t* Ag = A + (long)mBase * lda + kOff;
  const bf16_t* Bg = Bt + (long)nBase * ldb + kOff;

  floatx4 acc[4][4];
#pragma unroll
  for (int i = 0; i < 4; i++)
#pragma unroll
    for (int j = 0; j < 4; j++) acc[i][j] = (floatx4){0.f, 0.f, 0.f, 0.f};

  auto stage = [&](int b, int k0) {
    async_load16(Ag + (long)rowA0 * lda + k0 + kblk * 8, &As[b][c0 * 512]);
    async_load16(Ag + (long)rowA1 * lda + k0 + kblk * 8, &As[b][c1 * 512]);
    async_load16(Bg + (long)rowA0 * ldb + k0 + kblk * 8, &Bs[b][c0 * 512]);
    async_load16(Bg + (long)rowA1 * ldb + k0 + kblk * 8, &Bs[b][c1 * 512]);
  };

  const int iters = keff / BK;
  stage(0, 0);
  stage(1, BK);

  int cur = 0;
  for (int it = 0; it < iters; it++) {
    // tile `it` landed (own 4 loads done; next tile's 4 may stay in flight);
    // lgkmcnt(0): our ds_reads of the buffer about to be re-staged are done.
    if (it + 1 < iters)
      asm volatile("s_waitcnt vmcnt(4) lgkmcnt(0)" ::: "memory");
    else
      asm volatile("s_waitcnt vmcnt(0) lgkmcnt(0)" ::: "memory");
    __builtin_amdgcn_s_barrier();
    if (it + 2 < iters) {
      int nb = cur + 2; if (nb >= 3) nb -= 3;
      stage(nb, (it + 2) * BK);
    }

    bf16x8 af[4], bfv[4];
#pragma unroll
    for (int i = 0; i < 4; i++)
      af[i] = lds_read8(&As[cur][(wr + i * 16 + lid) * BK + rq0]);
#pragma unroll
    for (int j = 0; j < 4; j++)
      bfv[j] = lds_read8(&Bs[cur][(wc + j * 16 + lid) * BK + rq0]);
#pragma unroll
    for (int i = 0; i < 4; i++)
#pragma unroll
      for (int j = 0; j < 4; j++)
        acc[i][j] = __builtin_amdgcn_mfma_f32_16x16x32_bf16(af[i], bfv[j],
                                                            acc[i][j], 0, 0, 0);
    cur = (cur == 2) ? 0 : cur + 1;
  }

#pragma unroll
  for (int i = 0; i < 4; i++) {
    const int mRow = mBase + wr + i * 16 + quad * 4;
#pragma unroll
    for (int j = 0; j < 4; j++) {
      const int n = nBase + wc + j * 16 + lid;
      if constexpr (MODE == 0) {
        const int which = n / 768;
        const int rem = n - which * 768;
        const int head = rem >> 6;
        const int d = rem & 63;
        const int b = mRow >> 11;
        const int t = mRow & 2047;
        const int bh = b * 12 + head;
        if (which == 2) {
          bf16x4 pk;
#pragma unroll
          for (int r = 0; r < 4; r++) pk[r] = (bf16_t)acc[i][j][r];
          const long off = ((long)bh * 64 + d) * 2048 + t;
          *reinterpret_cast<bf16x4*>(&vt_out[off]) = pk;
        } else if (which == 0) {
          // q scale folds softmax's log2e: flash computes p = exp2(s) direct
#pragma unroll
          for (int r = 0; r < 4; r++)
            q_out[((long)bh * 2048 + t + r) * 64 + d] =
                (bf16_t)(acc[i][j][r] * (0.125f * 1.44269504f));
        } else {
#pragma unroll
          for (int r = 0; r < 4; r++)
            k_out[((long)bh * 2048 + t + r) * 64 + d] = (bf16_t)acc[i][j][r];
        }
      } else if constexpr (MODE == 2) {  // GELU
        const float bv = bias[n];
#pragma unroll
        for (int r = 0; r < 4; r++) {
          float v = acc[i][j][r] + bv;
          float ge = 0.5f * v * (1.0f + erff(v * 0.70710678118654752f));
          out_bf[(long)(mRow + r) * Nld + n] = (bf16_t)ge;
        }
      } else if constexpr (MODE == 3) {  // proj: resid + acc + bias (fp32)
        const float bv = bias[n];
#pragma unroll
        for (int r = 0; r < 4; r++) {
          const long off = (long)(mRow + r) * Nld + n;
          out_f[off] = resid_f[off] + acc[i][j][r] + bv;
        }
      } else {  // MODE 4: HW fp32 atomic accumulate (out pre-initialized)
#pragma unroll
        for (int r = 0; r < 4; r++) {
          const long off = (long)(mRow + r) * Nld + n;
          unsafeAtomicAdd(&out_f[off], acc[i][j][r]);
        }
      }
    }
  }
}

// ---------------------------------------------------------------------------
// Flash v10: 512 threads (8 waves x 16 qrows), QT=128, SK=64.
// Grid (16, 24, 2): z = K-half (1024 tokens = 16 chunks each).
// 3-buffer K/V staging, 2-deep prefetch, counted vmcnt.
// Bias-free softmax (q pre-scaled 0.125*log2e -> p = exp2(s)).
// In-register P-transpose (v_cvt_pk_bf16_f32 + permlane32/16_swap).
// l via ones-MFMA (D-layout, lanes lid==0 write 4 rows each).
// setprio around MFMA clusters.
// Outputs UNNORMALIZED U (bf16, [half][bh][t][d]) and l (fp32).
// ---------------------------------------------------------------------------
__global__ __launch_bounds__(512, 1) void flash_k(const bf16_t* __restrict__ q,
                                                  const bf16_t* __restrict__ kk,
                                                  const bf16_t* __restrict__ vt,
                                                  bf16_t* __restrict__ U,
                                                  float* __restrict__ lbuf) {
  constexpr int SK = 64, D = 64;
  __shared__ __align__(16) bf16_t Ks[3][SK * D];
  __shared__ __align__(16) bf16_t Vs[3][D * SK];

  const int tid = threadIdx.x;
  const int w = tid >> 6;         // 0..7
  const int lane = tid & 63;
  const int quad = lane >> 4;
  const int lid = lane & 15;
  const int bh = blockIdx.y;
  const int half = blockIdx.z;
  const int qBase = blockIdx.x * 128;

  const bf16_t* qg = q + ((long)bh * 2048 + qBase) * D;
  const bf16_t* kg = kk + ((long)bh * 2048 + half * 1024) * D;
  const bf16_t* vg = vt + (long)bh * D * 2048 + half * 1024;

  // Q fragment in registers: B-operand, qrow = w*16+lid
  bf16x8 aq[2];
#pragma unroll
  for (int k2 = 0; k2 < 2; k2++)
    aq[k2] = *reinterpret_cast<const bf16x8*>(qg + (w * 16 + lid) * D +
                                              k2 * 32 + quad * 8);

  // all-ones B-fragment for the l-MFMA
  const bf16_t one = (bf16_t)1.0f;
  const bf16x8 vones = {one, one, one, one, one, one, one, one};

  const int srow = lane >> 3;           // 0..7
  const int sdb = (lane & 7) ^ srow;    // swizzled 16B block
  const int rsw = lid & 7;

  // wave w stages rows w*8..w*8+7 of K and V for chunk kc
  auto stagef = [&](int b, int kc) {
    async_load16(kg + (long)(kc + w * 8 + srow) * D + sdb * 8, &Ks[b][w * 512]);
    async_load16(vg + (long)(w * 8 + srow) * 2048 + kc + sdb * 8, &Vs[b][w * 512]);
  };

  stagef(0, 0);
  stagef(1, 64);

  floatx4 lacc = (floatx4){0.f, 0.f, 0.f, 0.f};
  floatx4 oacc[4];
#pragma unroll
  for (int jo = 0; jo < 4; jo++) oacc[jo] = (floatx4){0.f, 0.f, 0.f, 0.f};

  int cur = 0;
  for (int kci = 0; kci < 16; kci++) {
    // tile kci landed (own 2 loads done; tile kci+1's 2 may stay in flight);
    // lgkmcnt(0): my ds_reads of the buffer about to be re-staged are done.
    if (kci + 1 < 16)
      asm volatile("s_waitcnt vmcnt(2) lgkmcnt(0)" ::: "memory");
    else
      asm volatile("s_waitcnt vmcnt(0) lgkmcnt(0)" ::: "memory");
    __builtin_amdgcn_s_barrier();
    if (kci + 2 < 16) {
      int nb = cur + 2; if (nb >= 3) nb -= 3;
      stagef(nb, (kci + 2) * 64);
    }

    // S^T = K Q^T  — sacc[jm] holds S[kt=jm*16+quad*4+r][q=lid]
    floatx4 sacc[4];
#pragma unroll
    for (int jm = 0; jm < 4; jm++) sacc[jm] = (floatx4){0.f, 0.f, 0.f, 0.f};
    __builtin_amdgcn_s_setprio(1);
#pragma unroll
    for (int k2 = 0; k2 < 2; k2++) {
#pragma unroll
      for (int jm = 0; jm < 4; jm++) {
        const bf16x8 ak = lds_read8(
            &Ks[cur][(jm * 16 + lid) * D + (((k2 * 4 + quad) ^ rsw) * 8)]);
        sacc[jm] =
            __builtin_amdgcn_mfma_f32_16x16x32_bf16(ak, aq[k2], sacc[jm], 0, 0, 0);
      }
    }
    __builtin_amdgcn_s_setprio(0);

    // p = exp2(s) (bias-free; log2e folded into q scale);
    // pack bf16 pairs; permlane-rotate to PV A-fragment layout.
    bf16x8 ap[2];
#pragma unroll
    for (int k2 = 0; k2 < 2; k2++) {
      uint32_t pk[2][2];
#pragma unroll
      for (int j = 0; j < 2; j++) {
        const int jm = k2 * 2 + j;
        const float p0 = exp2f(sacc[jm][0]);
        const float p1 = exp2f(sacc[jm][1]);
        const float p2 = exp2f(sacc[jm][2]);
        const float p3 = exp2f(sacc[jm][3]);
        asm("v_cvt_pk_bf16_f32 %0, %1, %2" : "=v"(pk[j][0]) : "v"(p0), "v"(p1));
        asm("v_cvt_pk_bf16_f32 %0, %1, %2" : "=v"(pk[j][1]) : "v"(p2), "v"(p3));
      }
      asm("v_permlane32_swap_b32 %0, %1" : "+v"(pk[0][0]), "+v"(pk[1][0]));
      asm("v_permlane16_swap_b32 %0, %1" : "+v"(pk[0][0]), "+v"(pk[1][0]));
      asm("v_permlane32_swap_b32 %0, %1" : "+v"(pk[0][1]), "+v"(pk[1][1]));
      asm("v_permlane16_swap_b32 %0, %1" : "+v"(pk[0][1]), "+v"(pk[1][1]));
      union { uint32_t u[4]; bf16x8 v; } au;
      au.u[0] = pk[0][0];  // kt +0,+1
      au.u[1] = pk[0][1];  // kt +2,+3
      au.u[2] = pk[1][0];  // kt +4,+5
      au.u[3] = pk[1][1];  // kt +6,+7
      ap[k2] = au.v;
    }

    // O += P V; l += P 1 (ones-MFMA: D[q][.] = sum_kt P[q][kt])
    __builtin_amdgcn_s_setprio(1);
#pragma unroll
    for (int k2 = 0; k2 < 2; k2++) {
#pragma unroll
      for (int jo = 0; jo < 4; jo++) {
        const bf16x8 bv = lds_read8(
            &Vs[cur][(jo * 16 + lid) * SK + (((k2 * 4 + quad) ^ rsw) * 8)]);
        oacc[jo] =
            __builtin_amdgcn_mfma_f32_16x16x32_bf16(ap[k2], bv, oacc[jo], 0, 0, 0);
      }
      lacc = __builtin_amdgcn_mfma_f32_16x16x32_bf16(ap[k2], vones, lacc, 0, 0, 0);
    }
    __builtin_amdgcn_s_setprio(0);
    cur = (cur == 2) ? 0 : cur + 1;
  }

  // store l: lacc[r] = l for qrow quad*4+r (replicated across lid);
  // lanes with lid==0 (one per quad) write 4 rows each.
  const long lrow = ((long)half * 24 + bh) * 2048 + qBase + w * 16;
  if (lid == 0) {
#pragma unroll
    for (int r = 0; r < 4; r++) lbuf[lrow + quad * 4 + r] = lacc[r];
  }

  // store unnormalized U[half][bh][t][d]
  bf16_t* Ub = U + (((long)half * 24 + bh) * 2048 + qBase) * D;
#pragma unroll
  for (int jo = 0; jo < 4; jo++) {
#pragma unroll
    for (int r = 0; r < 4; r++) {
      const int t = w * 16 + quad * 4 + r;
      Ub[(long)t * D + jo * 16 + lid] = (bf16_t)oacc[jo][r];
    }
  }
}

// ---------------------------------------------------------------------------
// Combine: o[b][t][head*64+d] = (U0+U1)/(l0+l1)
// ---------------------------------------------------------------------------
__global__ __launch_bounds__(256) void combine_k(const bf16_t* __restrict__ U,
                                                 const float* __restrict__ lbuf,
                                                 bf16_t* __restrict__ o) {
  const int idx = blockIdx.x * 256 + threadIdx.x;  // < 3145728
  const int bh = idx >> 17;
  const int rem = idx & 131071;
  const int t = rem >> 6;
  const int d = rem & 63;
  const float l0 = lbuf[bh * 2048 + t];
  const float l1 = lbuf[(24 + bh) * 2048 + t];
  const float u = (float)U[idx] + (float)U[3145728 + idx];
  const int b = bh / 12;
  const int head = bh - b * 12;
  o[((long)b * 2048 + t) * 768 + head * 64 + d] = (bf16_t)(u / (l0 + l1));
}

// ---------------------------------------------------------------------------
extern "C" void kernel_launch(void* const* d_in, const int* in_sizes, int n_in,
                              void* d_out, int out_size, void* d_ws,
                              size_t ws_size, hipStream_t stream) {
  (void)in_sizes; (void)n_in; (void)out_size;
  const float* x = (const float*)d_in[0];
  const float* ln1_g = (const float*)d_in[1];
  const float* ln1_b = (const float*)d_in[2];
  const float* qkv_w = (const float*)d_in[3];
  const float* proj_w = (const float*)d_in[4];
  const float* proj_b = (const float*)d_in[5];
  const float* ln2_g = (const float*)d_in[6];
  const float* ln2_b = (const float*)d_in[7];
  const float* fc1_w = (const float*)d_in[8];
  const float* fc1_b = (const float*)d_in[9];
  const float* fc2_w = (const float*)d_in[10];
  const float* fc2_b = (const float*)d_in[11];
  float* out = (float*)d_out;
  char* ws = (char*)d_ws;

  const bool big = ws_size >= (size_t)64487424;

  if (big) {
    // big layout:
    // wqkv[0,3538944) wproj[3538944,4718592) wfc1[4718592,9437184)
    // wfc2[9437184,14155776) h1/ob[14155776,20447232) qb[20447232,26738688)
    // kb[26738688,33030144) vtb[33030144,39321600)
    // U[39321600,51904512) l[51904512,52297728)
    // x1 over qb+kb [20447232,33030144); h2 over vtb; hg [39321600,64487424)
    bf16_t* wqkv = (bf16_t*)(ws + 0);
    bf16_t* wproj = (bf16_t*)(ws + 3538944);
    bf16_t* wfc1 = (bf16_t*)(ws + 4718592);
    bf16_t* wfc2 = (bf16_t*)(ws + 9437184);
    bf16_t* h1 = (bf16_t*)(ws + 14155776);
    bf16_t* ob = h1;
    bf16_t* qb = (bf16_t*)(ws + 20447232);
    bf16_t* kb = (bf16_t*)(ws + 26738688);
    bf16_t* vtb = (bf16_t*)(ws + 33030144);
    bf16_t* Ubuf = (bf16_t*)(ws + 39321600);
    float* lbuf = (float*)(ws + 51904512);
    float* x1 = (float*)(ws + 20447232);
    bf16_t* h2 = (bf16_t*)(ws + 33030144);
    bf16_t* hg = (bf16_t*)(ws + 39321600);

    cvt_all_k<<<6912, 256, 0, stream>>>(qkv_w, proj_w, fc1_w, fc2_w, wqkv,
                                        wproj, wfc1, wfc2);
    ln_k<0><<<4096, 256, 0, stream>>>(x, ln1_g, ln1_b, h1, nullptr, nullptr);
    gemm_k<0><<<dim3(32, 18), 256, 0, stream>>>(h1, wqkv, 768, 768, 768, 2304,
                                                nullptr, nullptr, qb, kb, vtb,
                                                nullptr, nullptr);
    flash_k<<<dim3(16, 24, 2), 512, 0, stream>>>(qb, kb, vtb, Ubuf, lbuf);
    combine_k<<<12288, 256, 0, stream>>>(Ubuf, lbuf, ob);
    gemm_k<3><<<dim3(32, 6), 256, 0, stream>>>(ob, wproj, 768, 768, 768, 768,
                                               proj_b, nullptr, nullptr,
                                               nullptr, nullptr, x, x1);
    ln_k<1><<<4096, 256, 0, stream>>>(x1, ln2_g, ln2_b, h2, fc2_b, out);
    gemm_k<2><<<dim3(32, 24), 256, 0, stream>>>(h2, wfc1, 768, 768, 768, 3072,
                                                fc1_b, hg, nullptr, nullptr,
                                                nullptr, nullptr, nullptr);
    gemm_k<4><<<dim3(32, 6, 2), 256, 0, stream>>>(hg, wfc2, 3072, 3072, 1536,
                                                  768, nullptr, nullptr,
                                                  nullptr, nullptr, nullptr,
                                                  nullptr, out);
  } else {
    // small layout (r12) + U/l in the free tail
    bf16_t* wqkv = (bf16_t*)(ws + 0);
    bf16_t* wproj = (bf16_t*)(ws + 3538944);
    bf16_t* h1 = (bf16_t*)(ws + 4718592);
    bf16_t* ob = h1;
    bf16_t* qb = (bf16_t*)(ws + 11010048);
    bf16_t* kb = (bf16_t*)(ws + 17301504);
    bf16_t* vtb = (bf16_t*)(ws + 23592960);
    float* x1 = (float*)(ws + 11010048);
    bf16_t* h2 = (bf16_t*)(ws + 23592960);
    bf16_t* wfc1 = (bf16_t*)(ws + 0);
    bf16_t* wfc2 = (bf16_t*)(ws + 4718592);
    bf16_t* hg = (bf16_t*)(ws + 29884416);
    bf16_t* Ubuf = (bf16_t*)(ws + 29884416);  // dead before hg is written
    float* lbuf = (float*)(ws + 42467328);

    cvt_k<<<1728, 256, 0, stream>>>(qkv_w, wqkv, 442368);
    cvt_k<<<576, 256, 0, stream>>>(proj_w, wproj, 147456);
    ln_k<0><<<4096, 256, 0, stream>>>(x, ln1_g, ln1_b, h1, nullptr, nullptr);
    gemm_k<0><<<dim3(32, 18), 256, 0, stream>>>(h1, wqkv, 768, 768, 768, 2304,
                                                nullptr, nullptr, qb, kb, vtb,
                                                nullptr, nullptr);
    flash_k<<<dim3(16, 24, 2), 512, 0, stream>>>(qb, kb, vtb, Ubuf, lbuf);
    combine_k<<<12288, 256, 0, stream>>>(Ubuf, lbuf, ob);
    gemm_k<3><<<dim3(32, 6), 256, 0, stream>>>(ob, wproj, 768, 768, 768, 768,
                                               proj_b, nullptr, nullptr,
                                               nullptr, nullptr, x, x1);
    cvt_k<<<2304, 256, 0, stream>>>(fc1_w, wfc1, 589824);
    cvt_k<<<2304, 256, 0, stream>>>(fc2_w, wfc2, 589824);
    ln_k<1><<<4096, 256, 0, stream>>>(x1, ln2_g, ln2_b, h2, fc2_b, out);
    for (int h = 0; h < 2; h++) {
      gemm_k<2><<<dim3(32, 12), 256, 0, stream>>>(
          h2, wfc1 + (long)h * 1536 * 768, 768, 768, 768, 1536,
          fc1_b + h * 1536, hg, nullptr, nullptr, nullptr, nullptr, nullptr);
      gemm_k<4><<<dim3(32, 6), 256, 0, stream>>>(hg, wfc2 + h * 1536, 1536,
                                                 3072, 1536, 768, nullptr,
                                                 nullptr, nullptr, nullptr,
                                                 nullptr, nullptr, out);
    }
  }
}